// Round 13
// baseline (479.604 us; speedup 1.0000x reference)
//
#include <hip/hip_runtime.h>

typedef float    v2f __attribute__((ext_vector_type(2)));
typedef unsigned v2u __attribute__((ext_vector_type(2)));

// Problem constants (from reference)
constexpr int CB   = 128;
constexpr int CC   = 12;
constexpr int CL   = 2048;
constexpr int CK   = 8;
constexpr int CG   = 32;
constexpr int CNCP = 6;
constexpr int CND  = 8;
constexpr int HALO = 512;   // max tap reach = 4*128
constexpr int BUF  = HALO + CL + HALO + 16;

// ---------------------------------------------------------------------------
// Transpose W [pair][g*8+k][9] -> Wt [pair][g][j*8+k].
// ---------------------------------------------------------------------------
__global__ void transposeW(const float* __restrict__ W, float* __restrict__ Wt) {
    int t = blockIdx.x * blockDim.x + threadIdx.x;
    constexpr int total = CND * 2 * CG * CK * 9; // 36864
    if (t >= total) return;
    int j = t % 9; int r = t / 9;
    int k = r % CK; r /= CK;
    int g = r % CG; int pair = r / CG;
    Wt[(pair * CG + g) * 72 + j * 8 + k] =
        W[((pair * (CG * CK)) + g * CK + k) * 9 + j];
}

__device__ __forceinline__ float4 ld4(const float* p) { return *(const float4*)p; }
__device__ __forceinline__ v2f vmax(v2f a, v2f b) { return __builtin_elementwise_max(a, b); }
__device__ __forceinline__ v2f vmin(v2f a, v2f b) { return __builtin_elementwise_min(a, b); }

// Guaranteed-packed fp32 FMA (VOP3P). w = uniform weight pair (SGPR64, the
// one legal scalar operand). tap = {t_l, t_l1}; op_sel broadcasts one half
// to both result halves -> zero broadcast instructions.
__device__ __forceinline__ v2f pk_fma_lo(v2f w, v2f tap, v2f acc) {
    v2f d;
    asm("v_pk_fma_f32 %0, %1, %2, %3 op_sel:[0,0,0] op_sel_hi:[1,0,1]"
        : "=v"(d) : "s"(w), "v"(tap), "v"(acc));
    return d;
}
__device__ __forceinline__ v2f pk_fma_hi(v2f w, v2f tap, v2f acc) {
    v2f d;
    asm("v_pk_fma_f32 %0, %1, %2, %3 op_sel:[0,1,0] op_sel_hi:[1,1,1]"
        : "=v"(d) : "s"(w), "v"(tap), "v"(acc));
    return d;
}

// Embed kernel index in low 3 mantissa bits (R11-proven); pair codes {2t,2t+1}.
__device__ __forceinline__ v2f packidx2(v2f a, unsigned c0, unsigned c1) {
    v2u u = __builtin_bit_cast(v2u, a);
    u = (u & 0xFFFFFFF8u) | (v2u){c0, c1};
    return __builtin_bit_cast(v2f, u);
}
__device__ __forceinline__ int lowbits(float v) {
    return (int)(__builtin_bit_cast(unsigned, v) & 7u);
}

// ---------------------------------------------------------------------------
// R12 structure (8192 blocks, XCD swizzle, reduce-scatter); conv rewritten as
// k-pair accumulators + op_sel-broadcast v_pk_fma_f32 (forced VOP3P).
// ---------------------------------------------------------------------------
__global__ void __launch_bounds__(256)
hydra_fused(const float* __restrict__ X, const float* __restrict__ Wt,
            const int* __restrict__ I, float* __restrict__ out)
{
    __shared__ float inp[BUF];
    __shared__ float wavehist[4 * 16];
    const int tid = threadIdx.x;
    const int blk  = blockIdx.x;
    const int x    = blk & 7;
    const int r    = blk >> 3;            // [0,1024)
    const int pair = r & 15;
    const int gq   = (r >> 4) & 3;
    const int b    = x * 16 + (r >> 6);
    const int di    = pair >> 1;
    const int diffi = pair & 1;
    const int D     = 1 << di;
    const int Lout  = CL - diffi;
    const float* __restrict__ Xb = X + (size_t)b * (CC * CL);

    for (int i = tid; i < HALO; i += 256) inp[i] = 0.f;
    for (int i = HALO + CL + tid; i < BUF; i += 256) inp[i] = 0.f;

    #pragma unroll 1
    for (int gi = 0; gi < 8; ++gi) {
        const int g = gq * 8 + gi;
        // ---- stage summed (and optionally diffed) row for this group ----
        const int* __restrict__ Ig = I + (pair * CG + g) * CNCP;
        const int ch0 = Ig[0], ch1 = Ig[1], ch2 = Ig[2],
                  ch3 = Ig[3], ch4 = Ig[4], ch5 = Ig[5];
        const float* r0 = Xb + ch0 * CL; const float* r1 = Xb + ch1 * CL;
        const float* r2 = Xb + ch2 * CL; const float* r3 = Xb + ch3 * CL;
        const float* r4 = Xb + ch4 * CL; const float* r5 = Xb + ch5 * CL;

        #pragma unroll
        for (int cc = 0; cc < 2; ++cc) {
            const int pos = cc * 1024 + tid * 4;
            const float4 x0 = ld4(r0 + pos), x1 = ld4(r1 + pos), x2 = ld4(r2 + pos),
                         x3 = ld4(r3 + pos), x4 = ld4(r4 + pos), x5 = ld4(r5 + pos);
            float4 s;
            s.x = ((x0.x + x1.x) + (x2.x + x3.x)) + (x4.x + x5.x);
            s.y = ((x0.y + x1.y) + (x2.y + x3.y)) + (x4.y + x5.y);
            s.z = ((x0.z + x1.z) + (x2.z + x3.z)) + (x4.z + x5.z);
            s.w = ((x0.w + x1.w) + (x2.w + x3.w)) + (x4.w + x5.w);
            if (!diffi) {
                *(float4*)&inp[HALO + pos] = s;
            } else {
                float s4;
                if (pos + 4 < CL)
                    s4 = ((r0[pos + 4] + r1[pos + 4]) + (r2[pos + 4] + r3[pos + 4]))
                         + (r4[pos + 4] + r5[pos + 4]);
                else
                    s4 = s.w; // => diff 0 at padding position 2047
                const float4 d = make_float4(s.y - s.x, s.z - s.y, s.w - s.z, s4 - s.w);
                *(float4*)&inp[HALO + pos] = d;
            }
        }
        __syncthreads();

        // ---- conv (k-pair accs, op_sel pk_fma) + select + register bins ----
        const float* __restrict__ Wg = Wt + (pair * CG + g) * 72;
        v2f bm0 = {0,0}, bm1 = {0,0}, bm2 = {0,0}, bm3 = {0,0},
            bm4 = {0,0}, bm5 = {0,0}, bm6 = {0,0}, bm7 = {0,0};
        unsigned bnpack = 0;

        #pragma unroll 1
        for (int p = 0; p < 4; ++p) {
            const int l = p * 512 + tid * 2;          // even; positions l, l+1
            v2f A[4] = {}, B[4] = {};   // A: pos l, B: pos l+1; k-pairs {2t,2t+1}

            // TV = {tap(l), tap(l+1)} for tap j; weights from SGPR pairs.
            #define FK2(J, TV) { const v2f tv_ = (TV); \
                const v2f w0 = *(const v2f*)(Wg + (J)*8 + 0); \
                const v2f w1 = *(const v2f*)(Wg + (J)*8 + 2); \
                const v2f w2 = *(const v2f*)(Wg + (J)*8 + 4); \
                const v2f w3 = *(const v2f*)(Wg + (J)*8 + 6); \
                A[0] = pk_fma_lo(w0, tv_, A[0]); A[1] = pk_fma_lo(w1, tv_, A[1]); \
                A[2] = pk_fma_lo(w2, tv_, A[2]); A[3] = pk_fma_lo(w3, tv_, A[3]); \
                B[0] = pk_fma_hi(w0, tv_, B[0]); B[1] = pk_fma_hi(w1, tv_, B[1]); \
                B[2] = pk_fma_hi(w2, tv_, B[2]); B[3] = pk_fma_hi(w3, tv_, B[3]); }

            if (di == 0) {
                const float* base = &inp[HALO + l - 4];
                const v2f W0 = *(const v2f*)(base + 0), W1 = *(const v2f*)(base + 2),
                          W2 = *(const v2f*)(base + 4), W3 = *(const v2f*)(base + 6),
                          W4 = *(const v2f*)(base + 8);
                FK2(0, W0)
                FK2(1, ((v2f){W0.y, W1.x}))
                FK2(2, W1)
                FK2(3, ((v2f){W1.y, W2.x}))
                FK2(4, W2)
                FK2(5, ((v2f){W2.y, W3.x}))
                FK2(6, W3)
                FK2(7, ((v2f){W3.y, W4.x}))
                FK2(8, W4)
            } else {
                const float* base = &inp[HALO + l - 4 * D];
                #pragma unroll
                for (int j = 0; j < 9; ++j) {
                    FK2(j, (*(const v2f*)(base + j * D)))
                }
            }
            #undef FK2

            // per-position select: pack idx, 3 pk_max + scalar fold
            const v2f qa0 = packidx2(A[0], 0, 1), qa1 = packidx2(A[1], 2, 3),
                      qa2 = packidx2(A[2], 4, 5), qa3 = packidx2(A[3], 6, 7);
            const v2f qb0 = packidx2(B[0], 0, 1), qb1 = packidx2(B[1], 2, 3),
                      qb2 = packidx2(B[2], 4, 5), qb3 = packidx2(B[3], 6, 7);

            const v2f ma = vmax(vmax(qa0, qa1), vmax(qa2, qa3));
            const v2f na = vmin(vmin(qa0, qa1), vmin(qa2, qa3));
            const v2f mb = vmax(vmax(qb0, qb1), vmax(qb2, qb3));
            const v2f nb = vmin(vmin(qb0, qb1), vmin(qb2, qb3));

            const float mx0 = fmaxf(ma.x, ma.y), mn0 = fminf(na.x, na.y);
            const float mx1 = fmaxf(mb.x, mb.y), mn1 = fminf(nb.x, nb.y);

            int mi0 = lowbits(mx0), mi1 = lowbits(mx1);
            const int ni0 = lowbits(mn0), ni1 = lowbits(mn1);

            const bool v1ok = (l + 1) < Lout;
            if (!v1ok) mi1 = 8;

            #define BINK(K) bm##K += (v2f){ (mi0 == (K)) ? mx0 : 0.f, \
                                            (mi1 == (K)) ? mx1 : 0.f };
            BINK(0) BINK(1) BINK(2) BINK(3) BINK(4) BINK(5) BINK(6) BINK(7)
            #undef BINK
            bnpack += (1u << (ni0 * 4)) + (v1ok ? (1u << (ni1 * 4)) : 0u);
        }

        // ---- fold parities, unpack nibbles ----
        float f0 = bm0.x + bm0.y, f1 = bm1.x + bm1.y, f2 = bm2.x + bm2.y,
              f3 = bm3.x + bm3.y, f4 = bm4.x + bm4.y, f5 = bm5.x + bm5.y,
              f6 = bm6.x + bm6.y, f7 = bm7.x + bm7.y;
        float h0 = (float)((bnpack >>  0) & 15), h1 = (float)((bnpack >>  4) & 15),
              h2 = (float)((bnpack >>  8) & 15), h3 = (float)((bnpack >> 12) & 15),
              h4 = (float)((bnpack >> 16) & 15), h5 = (float)((bnpack >> 20) & 15),
              h6 = (float)((bnpack >> 24) & 15), h7 = (float)((bnpack >> 28) & 15);

        // ---- reduce-scatter over 64 lanes (R10-proven, 10 shuffles/set) ----
        const int lane = tid & 63;
        const bool l5 = (lane & 32) != 0, l4 = (lane & 16) != 0, l3 = (lane & 8) != 0;

        #define RSCAT(q, v0, v1, v2, v3, v4, v5, v6, v7)                          \
            float q;                                                              \
            {                                                                     \
                float k0 = l5 ? v4 : v0, s0 = l5 ? v0 : v4;                       \
                float k1 = l5 ? v5 : v1, s1 = l5 ? v1 : v5;                       \
                float k2 = l5 ? v6 : v2, s2 = l5 ? v2 : v6;                       \
                float k3 = l5 ? v7 : v3, s3 = l5 ? v3 : v7;                       \
                k0 += __shfl_xor(s0, 32); k1 += __shfl_xor(s1, 32);               \
                k2 += __shfl_xor(s2, 32); k3 += __shfl_xor(s3, 32);               \
                float m0 = l4 ? k2 : k0, t0 = l4 ? k0 : k2;                       \
                float m1 = l4 ? k3 : k1, t1 = l4 ? k1 : k3;                       \
                m0 += __shfl_xor(t0, 16); m1 += __shfl_xor(t1, 16);               \
                q = l3 ? m1 : m0; float u = l3 ? m0 : m1;                         \
                q += __shfl_xor(u, 8);                                            \
                q += __shfl_xor(q, 4); q += __shfl_xor(q, 2);                     \
                q += __shfl_xor(q, 1);                                            \
            }
        RSCAT(qf, f0, f1, f2, f3, f4, f5, f6, f7)
        RSCAT(qc, h0, h1, h2, h3, h4, h5, h6, h7)
        #undef RSCAT

        if ((lane & 7) == 0) {
            const int bin = (l5 ? 4 : 0) + (l4 ? 2 : 0) + (l3 ? 1 : 0);
            float* wh = wavehist + (tid >> 6) * 16;
            wh[bin]     = qf;
            wh[8 + bin] = qc;
        }
        __syncthreads();

        if (tid < 16) {
            const float s = wavehist[tid] + wavehist[16 + tid]
                          + wavehist[32 + tid] + wavehist[48 + tid];
            const int which = tid >> 3, k = tid & 7;
            out[(size_t)b * 8192 + ((pair * 2 + which) * CG + g) * CK + k] = s;
        }
    }
}

extern "C" void kernel_launch(void* const* d_in, const int* in_sizes, int n_in,
                              void* d_out, int out_size, void* d_ws, size_t ws_size,
                              hipStream_t stream)
{
    const float* X = (const float*)d_in[0];
    const float* W = (const float*)d_in[1];
    const int*   I = (const int*)d_in[2];
    float* out = (float*)d_out;
    float* Wt  = (float*)d_ws; // 36864 floats = 144 KiB scratch

    transposeW<<<dim3((36864 + 255) / 256), dim3(256), 0, stream>>>(W, Wt);
    // 128 b x 16 pair x 4 gq = 8192 blocks -> 4+ generations w/ backfill
    hydra_fused<<<dim3(CB * 16 * 4), dim3(256), 0, stream>>>(X, Wt, I, out);
}